// Round 1
// baseline (2022.669 us; speedup 1.0000x reference)
//
#include <hip/hip_runtime.h>

// ---------------------------------------------------------------------------
// Problem constants: B=2, L=1024, D=1024, H=16, DK=DV=64
// ---------------------------------------------------------------------------

#define TILE_M 64
#define TILE_N 64
#define TILE_K 16

struct GemmSlot { const float* W; const float* bias; float* out; int mode; };
struct GemmBatch { GemmSlot s[4]; };

__device__ __forceinline__ float silu_(float x) {
  return x / (1.f + __expf(-x));
}
__device__ __forceinline__ float sigm_(float x) {
  return 1.f / (1.f + __expf(-x));
}

// ---------------------------------------------------------------------------
// Generic fp32 GEMM: C = act(A[M,K] @ W[K,N] + bias), act/store per mode.
// mode 0: raw, linear store out[m*N+n]
// mode 1: silu, linear store
// mode 2: silu, scatter to [B,H,L,64]  (n -> (h,d), m -> (b,l))
// ---------------------------------------------------------------------------
__global__ __launch_bounds__(256) void gemm_act(
    const float* __restrict__ A, GemmBatch gb, int M, int N, int K)
{
  const GemmSlot sl = gb.s[blockIdx.z];
  const float* __restrict__ W = sl.W;

  __shared__ float As[TILE_K][TILE_M + 4];  // transposed A tile, padded
  __shared__ float Ws[TILE_K][TILE_N];

  const int tid = threadIdx.x;
  const int bm = blockIdx.x * TILE_M;
  const int bn = blockIdx.y * TILE_N;
  const int tm = (tid >> 4) << 2;   // 0..60
  const int tn = (tid & 15) << 2;   // 0..60
  const int la_r = tid >> 2;        // 0..63
  const int la_c = (tid & 3) << 2;  // 0,4,8,12
  const int lw_r = tid >> 4;        // 0..15
  const int lw_c = (tid & 15) << 2; // 0..60

  float acc[4][4] = {{0.f,0.f,0.f,0.f},{0.f,0.f,0.f,0.f},
                     {0.f,0.f,0.f,0.f},{0.f,0.f,0.f,0.f}};

  for (int kb = 0; kb < K; kb += TILE_K) {
    float4 av = *(const float4*)&A[(size_t)(bm + la_r) * K + kb + la_c];
    float4 wv = *(const float4*)&W[(size_t)(kb + lw_r) * N + bn + lw_c];
    __syncthreads();
    As[la_c + 0][la_r] = av.x;
    As[la_c + 1][la_r] = av.y;
    As[la_c + 2][la_r] = av.z;
    As[la_c + 3][la_r] = av.w;
    *(float4*)&Ws[lw_r][lw_c] = wv;
    __syncthreads();
#pragma unroll
    for (int kk = 0; kk < TILE_K; ++kk) {
      float4 a = *(const float4*)&As[kk][tm];
      float4 b = *(const float4*)&Ws[kk][tn];
      acc[0][0] = fmaf(a.x, b.x, acc[0][0]);
      acc[0][1] = fmaf(a.x, b.y, acc[0][1]);
      acc[0][2] = fmaf(a.x, b.z, acc[0][2]);
      acc[0][3] = fmaf(a.x, b.w, acc[0][3]);
      acc[1][0] = fmaf(a.y, b.x, acc[1][0]);
      acc[1][1] = fmaf(a.y, b.y, acc[1][1]);
      acc[1][2] = fmaf(a.y, b.z, acc[1][2]);
      acc[1][3] = fmaf(a.y, b.w, acc[1][3]);
      acc[2][0] = fmaf(a.z, b.x, acc[2][0]);
      acc[2][1] = fmaf(a.z, b.y, acc[2][1]);
      acc[2][2] = fmaf(a.z, b.z, acc[2][2]);
      acc[2][3] = fmaf(a.z, b.w, acc[2][3]);
      acc[3][0] = fmaf(a.w, b.x, acc[3][0]);
      acc[3][1] = fmaf(a.w, b.y, acc[3][1]);
      acc[3][2] = fmaf(a.w, b.z, acc[3][2]);
      acc[3][3] = fmaf(a.w, b.w, acc[3][3]);
    }
  }

  const float* bias = sl.bias;
  float* out = sl.out;
  const int mode = sl.mode;
#pragma unroll
  for (int i = 0; i < 4; ++i) {
#pragma unroll
    for (int j = 0; j < 4; ++j) {
      int m = bm + tm + i, n = bn + tn + j;
      float c = acc[i][j] + bias[n];
      if (mode >= 1) c = silu_(c);
      if (mode == 2) {
        int h = n >> 6, d = n & 63;
        int b = m >> 10, l = m & 1023;
        out[(((size_t)(b * 16 + h)) * 1024 + l) * 64 + d] = c;
      } else {
        out[(size_t)m * N + n] = c;
      }
    }
  }
}

// ---------------------------------------------------------------------------
// Scalar projections: 5 arrays [B*H, L], sigmoid(hs @ W[:,h] + bias + extra)
// One thread per (row m, col c) of the 2048 x 80 output.
// ---------------------------------------------------------------------------
__global__ __launch_bounds__(256) void scalar_proj(
    const float* __restrict__ hs,
    const float* __restrict__ Wb,  const float* __restrict__ bb,
    const float* __restrict__ Wfd, const float* __restrict__ bfd, const float* __restrict__ fdb,
    const float* __restrict__ Wsd, const float* __restrict__ bsd, const float* __restrict__ sdb,
    const float* __restrict__ Wfg, const float* __restrict__ bfg,
    const float* __restrict__ Wsg, const float* __restrict__ bsg,
    float* __restrict__ beta_o, float* __restrict__ fd_o, float* __restrict__ sd_o,
    float* __restrict__ fg_o, float* __restrict__ sg_o)
{
  int gid = blockIdx.x * 256 + threadIdx.x;  // < 2048*80
  int m = gid / 80;
  int c = gid - m * 80;
  int type = c >> 4;
  int h = c & 15;
  const float* W; const float* bias; float extra = 0.f; float* out;
  switch (type) {
    case 0:  W = Wb;  bias = bb;  out = beta_o; break;
    case 1:  W = Wfd; bias = bfd; extra = fdb[h]; out = fd_o; break;
    case 2:  W = Wsd; bias = bsd; extra = sdb[h]; out = sd_o; break;
    case 3:  W = Wfg; bias = bfg; out = fg_o; break;
    default: W = Wsg; bias = bsg; out = sg_o; break;
  }
  const float* hrow = hs + (size_t)m * 1024;
  float s = 0.f;
  for (int k2 = 0; k2 < 1024; ++k2)
    s = fmaf(hrow[k2], W[k2 * 16 + h], s);
  s += bias[h] + extra;
  float r = sigm_(s);
  int b = m >> 10, l = m & 1023;
  out[(size_t)(b * 16 + h) * 1024 + l] = r;
}

// ---------------------------------------------------------------------------
// Sequential scan: one block per (b,h). 256 threads = 4 waves.
// Wave w owns state rows [16w, 16w+16); lane owns column v.
// ---------------------------------------------------------------------------
__global__ __launch_bounds__(256) void scan_kernel(
    const float* __restrict__ qg, const float* __restrict__ kg, const float* __restrict__ vg,
    const float* __restrict__ beta_g, const float* __restrict__ fd_g, const float* __restrict__ sd_g,
    const float* __restrict__ fg_g, const float* __restrict__ sg_g,
    const float* __restrict__ rfx, float* __restrict__ og)
{
  const int bh = blockIdx.x;   // 0..31
  const int tid = threadIdx.x;
  const int lane = tid & 63;
  const int w = tid >> 6;
  const float rf = rfx[0];

  __shared__ float ks[64];
  __shared__ float qs[64];
  __shared__ float2 p2[4][64];
  __shared__ float2 nrm2[4];

  float Sf[16], Ss[16];
#pragma unroll
  for (int i = 0; i < 16; ++i) { Sf[i] = 0.f; Ss[i] = 0.f; }

  const float* qb = qg + (size_t)bh * (1024 * 64);
  const float* kb = kg + (size_t)bh * (1024 * 64);
  const float* vb = vg + (size_t)bh * (1024 * 64);
  const float* betab = beta_g + (size_t)bh * 1024;
  const float* fdb2  = fd_g   + (size_t)bh * 1024;
  const float* sdb2  = sd_g   + (size_t)bh * 1024;
  const float* fgb   = fg_g   + (size_t)bh * 1024;
  const float* sgb   = sg_g   + (size_t)bh * 1024;
  const int b = bh >> 4, h = bh & 15;
  float* ob = og + (size_t)b * (1024 * 16 * 64) + h * 64;  // + t*1024 + lane

  for (int t = 0; t < 1024; ++t) {
    // ---- phase A: per-step uniforms, q/k L2-normalize into LDS, decay ----
    const float fdt = fdb2[t], sdt = sdb2[t], bt = betab[t];
    const float fgt = fgb[t],  sgt = sgb[t];
    const float vval = vb[(size_t)t * 64 + lane];
    if (w == 0) {
      float x = kb[(size_t)t * 64 + lane];
      float ssum = x * x;
#pragma unroll
      for (int d2 = 32; d2 >= 1; d2 >>= 1) ssum += __shfl_xor(ssum, d2, 64);
      ks[lane] = x * rsqrtf(ssum + 1e-6f);
    } else if (w == 1) {
      float x = qb[(size_t)t * 64 + lane];
      float ssum = x * x;
#pragma unroll
      for (int d2 = 32; d2 >= 1; d2 >>= 1) ssum += __shfl_xor(ssum, d2, 64);
      qs[lane] = x * rsqrtf(ssum + 1e-6f);
    }
#pragma unroll
    for (int i = 0; i < 16; ++i) { Sf[i] *= fdt; Ss[i] *= sdt; }
    __syncthreads();  // B1

    // ---- phase B: err-dot partials over this wave's 16 rows ----
    float kr[16];
    *(float4*)&kr[0]  = *(const float4*)&ks[w * 16 + 0];
    *(float4*)&kr[4]  = *(const float4*)&ks[w * 16 + 4];
    *(float4*)&kr[8]  = *(const float4*)&ks[w * 16 + 8];
    *(float4*)&kr[12] = *(const float4*)&ks[w * 16 + 12];
    float ef = 0.f, es = 0.f;
#pragma unroll
    for (int i = 0; i < 16; ++i) {
      ef = fmaf(kr[i], Sf[i], ef);
      es = fmaf(kr[i], Ss[i], es);
    }
    p2[w][lane] = make_float2(ef, es);
    __syncthreads();  // B2

    // ---- phase C: finish err, rank-1 update, resonance combine, norm ----
    float2 pa = p2[0][lane], pb = p2[1][lane], pc = p2[2][lane], pd = p2[3][lane];
    float errf = vval - (pa.x + pb.x + pc.x + pd.x);
    float errs = vval - (pa.y + pb.y + pc.y + pd.y);
    float bef = bt * errf, bes = bt * errs;
    float nf = 0.f, ns = 0.f;
#pragma unroll
    for (int i = 0; i < 16; ++i) {
      float sfv = fmaf(kr[i], bef, Sf[i]);
      float ssv = fmaf(kr[i], bes, Ss[i]);
      float tf = fmaf(rf, ssv, sfv);
      float ts = fmaf(rf, sfv, ssv);
      nf = fmaf(tf, tf, nf);
      ns = fmaf(ts, ts, ns);
      Sf[i] = tf; Ss[i] = ts;
    }
#pragma unroll
    for (int d2 = 32; d2 >= 1; d2 >>= 1) {
      nf += __shfl_xor(nf, d2, 64);
      ns += __shfl_xor(ns, d2, 64);
    }
    if (lane == 0) nrm2[w] = make_float2(nf, ns);
    __syncthreads();  // B3

    // ---- phase D: cap scales, apply, output-dot partials ----
    float2 n0 = nrm2[0], n1 = nrm2[1], n2 = nrm2[2], n3 = nrm2[3];
    float Nf = n0.x + n1.x + n2.x + n3.x;
    float Ns = n0.y + n1.y + n2.y + n3.y;
    float nfs = sqrtf(Nf), nss = sqrtf(Ns);
    float scf = (nfs > 64.f) ? (64.f / nfs) : 1.f;
    float scs = (nss > 64.f) ? (64.f / nss) : 1.f;
    float qr[16];
    *(float4*)&qr[0]  = *(const float4*)&qs[w * 16 + 0];
    *(float4*)&qr[4]  = *(const float4*)&qs[w * 16 + 4];
    *(float4*)&qr[8]  = *(const float4*)&qs[w * 16 + 8];
    *(float4*)&qr[12] = *(const float4*)&qs[w * 16 + 12];
    float of = 0.f, os = 0.f;
#pragma unroll
    for (int i = 0; i < 16; ++i) {
      Sf[i] *= scf; Ss[i] *= scs;
      of = fmaf(qr[i], Sf[i], of);
      os = fmaf(qr[i], Ss[i], os);
    }
    p2[w][lane] = make_float2(of, os);
    __syncthreads();  // B4

    // ---- phase E: wave 0 combines and stores o[b,t,h,:] ----
    if (w == 0) {
      float2 r0 = p2[0][lane], r1 = p2[1][lane], r2 = p2[2][lane], r3 = p2[3][lane];
      float oo = fgt * (r0.x + r1.x + r2.x + r3.x)
               + sgt * (r0.y + r1.y + r2.y + r3.y);
      ob[(size_t)t * 1024 + lane] = oo;
    }
  }
}

// ---------------------------------------------------------------------------
// Gated RMSNorm: og = o * rsqrt(mean(o^2)+eps) * onorm_w * silu_g   (g pre-silu'd)
// One wave per (b,l,h) group of 64.
// ---------------------------------------------------------------------------
__global__ __launch_bounds__(256) void rms_gate(
    const float* __restrict__ o, const float* __restrict__ gsil,
    const float* __restrict__ onw, float* __restrict__ og)
{
  int gi = blockIdx.x * 4 + (threadIdx.x >> 6);
  int lane = threadIdx.x & 63;
  size_t idx = (size_t)gi * 64 + lane;
  float x = o[idx];
  float ss = x * x;
#pragma unroll
  for (int d2 = 32; d2 >= 1; d2 >>= 1) ss += __shfl_xor(ss, d2, 64);
  float r = rsqrtf(ss * (1.f / 64.f) + 1e-5f);
  og[idx] = x * r * onw[lane] * gsil[idx];
}

// ---------------------------------------------------------------------------
// Host launcher
// ---------------------------------------------------------------------------
extern "C" void kernel_launch(void* const* d_in, const int* in_sizes, int n_in,
                              void* d_out, int out_size, void* d_ws, size_t ws_size,
                              hipStream_t stream)
{
  const float* hs  = (const float*)d_in[0];
  const float* Wq  = (const float*)d_in[1];
  const float* bq  = (const float*)d_in[2];
  const float* Wk  = (const float*)d_in[3];
  const float* bk  = (const float*)d_in[4];
  const float* Wv  = (const float*)d_in[5];
  const float* bv  = (const float*)d_in[6];
  const float* Wb  = (const float*)d_in[7];
  const float* bb  = (const float*)d_in[8];
  const float* Wfd = (const float*)d_in[9];
  const float* bfd = (const float*)d_in[10];
  const float* fdb = (const float*)d_in[11];
  const float* Wsd = (const float*)d_in[12];
  const float* bsd = (const float*)d_in[13];
  const float* sdb = (const float*)d_in[14];
  const float* Wfg = (const float*)d_in[15];
  const float* bfg = (const float*)d_in[16];
  const float* Wsg = (const float*)d_in[17];
  const float* bsg = (const float*)d_in[18];
  const float* Wg  = (const float*)d_in[19];
  const float* bg  = (const float*)d_in[20];
  const float* onw = (const float*)d_in[21];
  const float* Wo  = (const float*)d_in[22];
  const float* bo  = (const float*)d_in[23];
  const float* rfx = (const float*)d_in[24];

  float* ws = (float*)d_ws;
  const size_t TWO_M = (size_t)1 << 21;  // 2M floats = B*H*L*64
  float* q_ws  = ws;
  float* k_ws  = ws + TWO_M;
  float* v_ws  = ws + 2 * TWO_M;
  float* g_ws  = ws + 3 * TWO_M;
  float* o_ws  = ws + 4 * TWO_M;
  float* beta_ws = ws + 5 * TWO_M;
  float* fd_ws = beta_ws + 32768;
  float* sd_ws = beta_ws + 2 * 32768;
  float* fg_ws = beta_ws + 3 * 32768;
  float* sg_ws = beta_ws + 4 * 32768;
  float* og_ws = q_ws;  // reuse q buffer (scan has consumed it)

  // 1) big projections: q,k,v (silu + scatter), g (silu, linear)
  GemmBatch gb1;
  gb1.s[0].W = Wq; gb1.s[0].bias = bq; gb1.s[0].out = q_ws; gb1.s[0].mode = 2;
  gb1.s[1].W = Wk; gb1.s[1].bias = bk; gb1.s[1].out = k_ws; gb1.s[1].mode = 2;
  gb1.s[2].W = Wv; gb1.s[2].bias = bv; gb1.s[2].out = v_ws; gb1.s[2].mode = 2;
  gb1.s[3].W = Wg; gb1.s[3].bias = bg; gb1.s[3].out = g_ws; gb1.s[3].mode = 1;
  gemm_act<<<dim3(32, 16, 4), 256, 0, stream>>>(hs, gb1, 2048, 1024, 1024);

  // 2) per-head scalar projections
  scalar_proj<<<640, 256, 0, stream>>>(hs, Wb, bb, Wfd, bfd, fdb, Wsd, bsd, sdb,
                                       Wfg, bfg, Wsg, bsg,
                                       beta_ws, fd_ws, sd_ws, fg_ws, sg_ws);

  // 3) sequential dual-state delta-rule scan
  scan_kernel<<<32, 256, 0, stream>>>(q_ws, k_ws, v_ws, beta_ws, fd_ws, sd_ws,
                                      fg_ws, sg_ws, rfx, o_ws);

  // 4) gated RMSNorm
  rms_gate<<<8192, 256, 0, stream>>>(o_ws, g_ws, onw, og_ws);

  // 5) output projection -> d_out
  GemmBatch gb2;
  gb2.s[0].W = Wo; gb2.s[0].bias = bo; gb2.s[0].out = (float*)d_out; gb2.s[0].mode = 0;
  gb2.s[1] = gb2.s[0]; gb2.s[2] = gb2.s[0]; gb2.s[3] = gb2.s[0];
  gemm_act<<<dim3(32, 16, 1), 256, 0, stream>>>(og_ws, gb2, 2048, 1024, 1024);
}

// Round 2
// 1922.254 us; speedup vs baseline: 1.0522x; 1.0522x over previous
//
#include <hip/hip_runtime.h>

// ---------------------------------------------------------------------------
// Problem constants: B=2, L=1024, D=1024, H=16, DK=DV=64
// ---------------------------------------------------------------------------

#define TILE_M 64
#define TILE_N 64
#define TILE_K 16

struct GemmSlot { const float* W; const float* bias; float* out; int mode; };
struct GemmBatch { GemmSlot s[4]; };

__device__ __forceinline__ float silu_(float x) {
  return x / (1.f + __expf(-x));
}
__device__ __forceinline__ float sigm_(float x) {
  return 1.f / (1.f + __expf(-x));
}

// ---------------------------------------------------------------------------
// Generic fp32 GEMM: C = act(A[M,K] @ W[K,N] + bias), act/store per mode.
// mode 0: raw, linear store out[m*N+n]
// mode 1: silu, linear store
// mode 2: silu, scatter to [B,H,L,64]  (n -> (h,d), m -> (b,l))
// ---------------------------------------------------------------------------
__global__ __launch_bounds__(256) void gemm_act(
    const float* __restrict__ A, GemmBatch gb, int M, int N, int K)
{
  const GemmSlot sl = gb.s[blockIdx.z];
  const float* __restrict__ W = sl.W;

  __shared__ float As[TILE_K][TILE_M + 4];  // transposed A tile, padded
  __shared__ float Ws[TILE_K][TILE_N];

  const int tid = threadIdx.x;
  const int bm = blockIdx.x * TILE_M;
  const int bn = blockIdx.y * TILE_N;
  const int tm = (tid >> 4) << 2;   // 0..60
  const int tn = (tid & 15) << 2;   // 0..60
  const int la_r = tid >> 2;        // 0..63
  const int la_c = (tid & 3) << 2;  // 0,4,8,12
  const int lw_r = tid >> 4;        // 0..15
  const int lw_c = (tid & 15) << 2; // 0..60

  float acc[4][4] = {{0.f,0.f,0.f,0.f},{0.f,0.f,0.f,0.f},
                     {0.f,0.f,0.f,0.f},{0.f,0.f,0.f,0.f}};

  for (int kb = 0; kb < K; kb += TILE_K) {
    float4 av = *(const float4*)&A[(size_t)(bm + la_r) * K + kb + la_c];
    float4 wv = *(const float4*)&W[(size_t)(kb + lw_r) * N + bn + lw_c];
    __syncthreads();
    As[la_c + 0][la_r] = av.x;
    As[la_c + 1][la_r] = av.y;
    As[la_c + 2][la_r] = av.z;
    As[la_c + 3][la_r] = av.w;
    *(float4*)&Ws[lw_r][lw_c] = wv;
    __syncthreads();
#pragma unroll
    for (int kk = 0; kk < TILE_K; ++kk) {
      float4 a = *(const float4*)&As[kk][tm];
      float4 b = *(const float4*)&Ws[kk][tn];
      acc[0][0] = fmaf(a.x, b.x, acc[0][0]);
      acc[0][1] = fmaf(a.x, b.y, acc[0][1]);
      acc[0][2] = fmaf(a.x, b.z, acc[0][2]);
      acc[0][3] = fmaf(a.x, b.w, acc[0][3]);
      acc[1][0] = fmaf(a.y, b.x, acc[1][0]);
      acc[1][1] = fmaf(a.y, b.y, acc[1][1]);
      acc[1][2] = fmaf(a.y, b.z, acc[1][2]);
      acc[1][3] = fmaf(a.y, b.w, acc[1][3]);
      acc[2][0] = fmaf(a.z, b.x, acc[2][0]);
      acc[2][1] = fmaf(a.z, b.y, acc[2][1]);
      acc[2][2] = fmaf(a.z, b.z, acc[2][2]);
      acc[2][3] = fmaf(a.z, b.w, acc[2][3]);
      acc[3][0] = fmaf(a.w, b.x, acc[3][0]);
      acc[3][1] = fmaf(a.w, b.y, acc[3][1]);
      acc[3][2] = fmaf(a.w, b.z, acc[3][2]);
      acc[3][3] = fmaf(a.w, b.w, acc[3][3]);
    }
  }

  const float* bias = sl.bias;
  float* out = sl.out;
  const int mode = sl.mode;
#pragma unroll
  for (int i = 0; i < 4; ++i) {
#pragma unroll
    for (int j = 0; j < 4; ++j) {
      int m = bm + tm + i, n = bn + tn + j;
      float c = acc[i][j] + bias[n];
      if (mode >= 1) c = silu_(c);
      if (mode == 2) {
        int h = n >> 6, d = n & 63;
        int b = m >> 10, l = m & 1023;
        out[(((size_t)(b * 16 + h)) * 1024 + l) * 64 + d] = c;
      } else {
        out[(size_t)m * N + n] = c;
      }
    }
  }
}

// ---------------------------------------------------------------------------
// Scalar projections, packed output: scl[bh][t][8] with
// slot 0=beta, 1=fd, 2=sd, 3=fg, 4=sg (5..7 pad). One thread per (m, c).
// ---------------------------------------------------------------------------
__global__ __launch_bounds__(256) void scalar_proj(
    const float* __restrict__ hs,
    const float* __restrict__ Wb,  const float* __restrict__ bb,
    const float* __restrict__ Wfd, const float* __restrict__ bfd, const float* __restrict__ fdb,
    const float* __restrict__ Wsd, const float* __restrict__ bsd, const float* __restrict__ sdb,
    const float* __restrict__ Wfg, const float* __restrict__ bfg,
    const float* __restrict__ Wsg, const float* __restrict__ bsg,
    float* __restrict__ scl)
{
  int gid = blockIdx.x * 256 + threadIdx.x;  // < 2048*80
  int m = gid / 80;
  int c = gid - m * 80;
  int type = c >> 4;
  int h = c & 15;
  const float* W; const float* bias; float extra = 0.f;
  switch (type) {
    case 0:  W = Wb;  bias = bb;  break;
    case 1:  W = Wfd; bias = bfd; extra = fdb[h]; break;
    case 2:  W = Wsd; bias = bsd; extra = sdb[h]; break;
    case 3:  W = Wfg; bias = bfg; break;
    default: W = Wsg; bias = bsg; break;
  }
  const float* hrow = hs + (size_t)m * 1024;
  float s = 0.f;
  for (int k2 = 0; k2 < 1024; ++k2)
    s = fmaf(hrow[k2], W[k2 * 16 + h], s);
  s += bias[h] + extra;
  float r = sigm_(s);
  int b = m >> 10, l = m & 1023;
  scl[((size_t)((b * 16 + h) * 1024 + l)) * 8 + type] = r;
}

// ---------------------------------------------------------------------------
// Sequential scan, column-split mapping: one block per (b,h), 4 waves.
// Wave w owns state COLUMNS [16w, 16w+16); lane (c=16w+(l&15), rowgrp r=l>>4)
// holds rows [16r,16r+16) of its column in registers (Sf[16], Ss[16]).
// k.S / q.S dots reduce via in-wave shfl_xor(16,32); only the Frobenius
// norm crosses waves -> 2 barriers/step (down from 4). Global loads for
// step t+1 are issued at the top of step t (software pipeline).
// ---------------------------------------------------------------------------
__global__ __launch_bounds__(256) void scan_kernel(
    const float* __restrict__ qg, const float* __restrict__ kg, const float* __restrict__ vg,
    const float* __restrict__ scl, const float* __restrict__ rfx, float* __restrict__ og)
{
  const int bh = blockIdx.x;   // 0..31
  const int tid = threadIdx.x;
  const int lane = tid & 63;
  const int w = tid >> 6;
  const int cl = lane & 15;    // column within wave
  const int r = lane >> 4;     // row group (0..3)
  const int c = w * 16 + cl;   // global column
  const float rf = rfx[0];

  __shared__ float ks[64];
  __shared__ float qs[64];
  __shared__ float2 nrm[4];

  float Sf[16], Ss[16];
#pragma unroll
  for (int j = 0; j < 16; ++j) { Sf[j] = 0.f; Ss[j] = 0.f; }

  // wave 0 loads+normalizes k, wave 1 does q; waves 2,3 skip that phase
  const float* kqb = ((w == 1) ? qg : kg) + (size_t)bh * 65536;
  const float* vb  = vg + (size_t)bh * 65536;
  const float* sb  = scl + (size_t)bh * 8192;
  const int b = bh >> 4, h = bh & 15;
  float* ob = og + (size_t)b * (1024 * 16 * 64) + h * 64;  // + t*1024 + c

  // preload t = 0
  float kqv = (w < 2) ? kqb[lane] : 0.f;
  float vv  = vb[c];
  float4 sc0 = *(const float4*)&sb[0];
  float sc4 = sb[4];

  for (int t = 0; t < 1024; ++t) {
    // ---- issue next-step loads (latency hides under this step's compute) ----
    const int tn = (t + 1) & 1023;  // wraps at end; values unused then
    float kqv_n = (w < 2) ? kqb[tn * 64 + lane] : 0.f;
    float vv_n  = vb[tn * 64 + c];
    float4 sc0_n = *(const float4*)&sb[(size_t)tn * 8];
    float sc4_n = sb[(size_t)tn * 8 + 4];

    const float bt = sc0.x, fdt = sc0.y, sdt = sc0.z, fgt = sc0.w, sgt = sc4;

    // ---- phase A: normalize k/q into LDS; decay state ----
    if (w < 2) {
      float ss = kqv * kqv;
#pragma unroll
      for (int d2 = 32; d2 >= 1; d2 >>= 1) ss += __shfl_xor(ss, d2, 64);
      float nv = kqv * rsqrtf(ss + 1e-6f);
      if (w == 0) ks[lane] = nv; else qs[lane] = nv;
    }
#pragma unroll
    for (int j = 0; j < 16; ++j) { Sf[j] *= fdt; Ss[j] *= sdt; }
    __syncthreads();  // B1: ks/qs visible

    // ---- phase B: err dots (in-wave reduce), rank-1 update, combine, norm ----
    float kr[16];
    *(float4*)&kr[0]  = *(const float4*)&ks[r * 16 + 0];
    *(float4*)&kr[4]  = *(const float4*)&ks[r * 16 + 4];
    *(float4*)&kr[8]  = *(const float4*)&ks[r * 16 + 8];
    *(float4*)&kr[12] = *(const float4*)&ks[r * 16 + 12];
    float ef = 0.f, es = 0.f;
#pragma unroll
    for (int j = 0; j < 16; ++j) {
      ef = fmaf(kr[j], Sf[j], ef);
      es = fmaf(kr[j], Ss[j], es);
    }
    ef += __shfl_xor(ef, 16, 64); ef += __shfl_xor(ef, 32, 64);
    es += __shfl_xor(es, 16, 64); es += __shfl_xor(es, 32, 64);
    const float errf = vv - ef, errs = vv - es;
    const float bef = bt * errf, bes = bt * errs;
    float nf = 0.f, ns = 0.f;
#pragma unroll
    for (int j = 0; j < 16; ++j) {
      float sfv = fmaf(kr[j], bef, Sf[j]);
      float ssv = fmaf(kr[j], bes, Ss[j]);
      float tf = fmaf(rf, ssv, sfv);
      float ts = fmaf(rf, sfv, ssv);
      nf = fmaf(tf, tf, nf);
      ns = fmaf(ts, ts, ns);
      Sf[j] = tf; Ss[j] = ts;
    }
#pragma unroll
    for (int d2 = 32; d2 >= 1; d2 >>= 1) {
      nf += __shfl_xor(nf, d2, 64);
      ns += __shfl_xor(ns, d2, 64);
    }
    if (lane == 0) nrm[w] = make_float2(nf, ns);
    float qr[16];  // read q fragment pre-B2 (qs stable in B1..B2 window)
    *(float4*)&qr[0]  = *(const float4*)&qs[r * 16 + 0];
    *(float4*)&qr[4]  = *(const float4*)&qs[r * 16 + 4];
    *(float4*)&qr[8]  = *(const float4*)&qs[r * 16 + 8];
    *(float4*)&qr[12] = *(const float4*)&qs[r * 16 + 12];
    __syncthreads();  // B2: nrm visible

    // ---- phase C: cap scales, apply, output dots (in-wave reduce), store ----
    float2 n0 = nrm[0], n1 = nrm[1], n2 = nrm[2], n3 = nrm[3];
    float nfs = sqrtf(n0.x + n1.x + n2.x + n3.x);
    float nss = sqrtf(n0.y + n1.y + n2.y + n3.y);
    float scf = (nfs > 64.f) ? (64.f / nfs) : 1.f;
    float scs = (nss > 64.f) ? (64.f / nss) : 1.f;
    float of = 0.f, os = 0.f;
#pragma unroll
    for (int j = 0; j < 16; ++j) {
      Sf[j] *= scf; Ss[j] *= scs;
      of = fmaf(qr[j], Sf[j], of);
      os = fmaf(qr[j], Ss[j], os);
    }
    of += __shfl_xor(of, 16, 64); of += __shfl_xor(of, 32, 64);
    os += __shfl_xor(os, 16, 64); os += __shfl_xor(os, 32, 64);
    if (r == 0) ob[(size_t)t * 1024 + c] = fgt * of + sgt * os;

    kqv = kqv_n; vv = vv_n; sc0 = sc0_n; sc4 = sc4_n;
  }
}

// ---------------------------------------------------------------------------
// Gated RMSNorm: og = o * rsqrt(mean(o^2)+eps) * onorm_w * silu_g (g pre-silu'd)
// ---------------------------------------------------------------------------
__global__ __launch_bounds__(256) void rms_gate(
    const float* __restrict__ o, const float* __restrict__ gsil,
    const float* __restrict__ onw, float* __restrict__ og)
{
  int gi = blockIdx.x * 4 + (threadIdx.x >> 6);
  int lane = threadIdx.x & 63;
  size_t idx = (size_t)gi * 64 + lane;
  float x = o[idx];
  float ss = x * x;
#pragma unroll
  for (int d2 = 32; d2 >= 1; d2 >>= 1) ss += __shfl_xor(ss, d2, 64);
  float r = rsqrtf(ss * (1.f / 64.f) + 1e-5f);
  og[idx] = x * r * onw[lane] * gsil[idx];
}

// ---------------------------------------------------------------------------
// Host launcher
// ---------------------------------------------------------------------------
extern "C" void kernel_launch(void* const* d_in, const int* in_sizes, int n_in,
                              void* d_out, int out_size, void* d_ws, size_t ws_size,
                              hipStream_t stream)
{
  const float* hs  = (const float*)d_in[0];
  const float* Wq  = (const float*)d_in[1];
  const float* bq  = (const float*)d_in[2];
  const float* Wk  = (const float*)d_in[3];
  const float* bk  = (const float*)d_in[4];
  const float* Wv  = (const float*)d_in[5];
  const float* bv  = (const float*)d_in[6];
  const float* Wb  = (const float*)d_in[7];
  const float* bb  = (const float*)d_in[8];
  const float* Wfd = (const float*)d_in[9];
  const float* bfd = (const float*)d_in[10];
  const float* fdb = (const float*)d_in[11];
  const float* Wsd = (const float*)d_in[12];
  const float* bsd = (const float*)d_in[13];
  const float* sdb = (const float*)d_in[14];
  const float* Wfg = (const float*)d_in[15];
  const float* bfg = (const float*)d_in[16];
  const float* Wsg = (const float*)d_in[17];
  const float* bsg = (const float*)d_in[18];
  const float* Wg  = (const float*)d_in[19];
  const float* bg  = (const float*)d_in[20];
  const float* onw = (const float*)d_in[21];
  const float* Wo  = (const float*)d_in[22];
  const float* bo  = (const float*)d_in[23];
  const float* rfx = (const float*)d_in[24];

  float* ws = (float*)d_ws;
  const size_t TWO_M = (size_t)1 << 21;  // 2M floats = B*H*L*64
  float* q_ws  = ws;
  float* k_ws  = ws + TWO_M;
  float* v_ws  = ws + 2 * TWO_M;
  float* g_ws  = ws + 3 * TWO_M;
  float* o_ws  = ws + 4 * TWO_M;
  float* scl_ws = ws + 5 * TWO_M;        // 32*1024*8 floats packed scalars
  float* og_ws = q_ws;  // reuse q buffer (scan has consumed it)

  // 1) big projections: q,k,v (silu + scatter), g (silu, linear)
  GemmBatch gb1;
  gb1.s[0].W = Wq; gb1.s[0].bias = bq; gb1.s[0].out = q_ws; gb1.s[0].mode = 2;
  gb1.s[1].W = Wk; gb1.s[1].bias = bk; gb1.s[1].out = k_ws; gb1.s[1].mode = 2;
  gb1.s[2].W = Wv; gb1.s[2].bias = bv; gb1.s[2].out = v_ws; gb1.s[2].mode = 2;
  gb1.s[3].W = Wg; gb1.s[3].bias = bg; gb1.s[3].out = g_ws; gb1.s[3].mode = 1;
  gemm_act<<<dim3(32, 16, 4), 256, 0, stream>>>(hs, gb1, 2048, 1024, 1024);

  // 2) per-head scalar projections (packed)
  scalar_proj<<<640, 256, 0, stream>>>(hs, Wb, bb, Wfd, bfd, fdb, Wsd, bsd, sdb,
                                       Wfg, bfg, Wsg, bsg, scl_ws);

  // 3) sequential dual-state delta-rule scan
  scan_kernel<<<32, 256, 0, stream>>>(q_ws, k_ws, v_ws, scl_ws, rfx, o_ws);

  // 4) gated RMSNorm
  rms_gate<<<8192, 256, 0, stream>>>(o_ws, g_ws, onw, og_ws);

  // 5) output projection -> d_out
  GemmBatch gb2;
  gb2.s[0].W = Wo; gb2.s[0].bias = bo; gb2.s[0].out = (float*)d_out; gb2.s[0].mode = 0;
  gb2.s[1] = gb2.s[0]; gb2.s[2] = gb2.s[0]; gb2.s[3] = gb2.s[0];
  gemm_act<<<dim3(32, 16, 1), 256, 0, stream>>>(og_ws, gb2, 2048, 1024, 1024);
}